// Round 4
// baseline (133.541 us; speedup 1.0000x reference)
//
#include <hip/hip_runtime.h>
#include <math.h>

// YOLOv1 loss: S=7, B=2, C=1, BATCH=32768
// predictions: (BATCH, 7, 7, 11) fp32   targets: (BATCH, 7, 7, 6) fp32
// out: 5 fp32 scalars: total, coord/bs, conf_obj/bs, conf_noobj/bs, class/bs
//
// v4: non-temporal direct loads. v1 (strided direct), v2 (LDS-DMA) and
// v3 (reg-staged coalesced) all hit the same ~2.5 TB/s read wall
// (4.2 B/cy/CU) -- per-CU read miss-tracking x latency, not coalescing,
// is the cap. FETCH_SIZE showed half the stream served by L3's scattered
// hit path. This version pulls the one untested knob: nt-bit loads
// (no L1 allocate, evict-first L2/L3 -> clean DRAM stream), on the
// simplest structure: direct per-cell exact-width loads (x4+x4+x3,
// x4+x2 -- no overlap, safe under nt), no LDS staging, no barrier,
// high occupancy, 2 cells/thread.

#define PRED_C 11
#define TGT_C  6
#define TPB    256
#define LAMBDA_COORD 5.0f
#define LAMBDA_NOOBJ 0.5f
#define EPSV 1e-6f

typedef float f4u __attribute__((ext_vector_type(4), aligned(4)));
typedef float f3u __attribute__((ext_vector_type(3), aligned(4)));
typedef float f2u __attribute__((ext_vector_type(2), aligned(4)));

__device__ __forceinline__ f4u nt4(const float* p) {
    return __builtin_nontemporal_load((const f4u*)p);
}
__device__ __forceinline__ f3u nt3(const float* p) {
    return __builtin_nontemporal_load((const f3u*)p);
}
__device__ __forceinline__ f2u nt2(const float* p) {
    return __builtin_nontemporal_load((const f2u*)p);
}

// fast sigmoid: |rel err| ~1e-6, far inside the absmax budget
__device__ __forceinline__ float fsig(float x) {
    return __builtin_amdgcn_rcpf(1.0f + __expf(-x));
}

// a = p[0..3], b = p[4..7], c3 = p[8..10], t4 = t[0..3], t2 = t[4..5]
// box0: x=a.x y=a.y w=a.z h=a.w conf=b.x
// box1: x=b.y y=b.z w=b.w h=c3.x conf=c3.y   class=c3.z
__device__ __forceinline__ void cell_loss(f4u a, f4u b, f3u c3, f4u t4, f2u t2,
                                          float& acc_coord, float& acc_cobj,
                                          float& acc_cnoobj, float& acc_cls)
{
    const float tx = t4.x, ty = t4.y, tw = t4.z, th = t4.w;
    const float tconf = t2.x, tcls = t2.y;
    const float obj   = (tconf == 1.0f) ? 1.0f : 0.0f;
    const float noobj = (tconf == 0.0f) ? 1.0f : 0.0f;

    const float t1x = tx - tw * 0.5f, t1y = ty - th * 0.5f;
    const float t2x = tx + tw * 0.5f, t2y = ty + th * 0.5f;
    const float tarea = tw * th;

    const float px[2] = { a.x, b.y };
    const float py[2] = { a.y, b.z };
    const float pw[2] = { a.z, b.w };
    const float ph[2] = { a.w, c3.x };
    const float pf[2] = { b.x, c3.y };

    float iou[2], sx[2], sy[2], aw[2], ah[2], scf[2];
    #pragma unroll
    for (int bb = 0; bb < 2; ++bb) {
        sx[bb]  = fsig(px[bb]);
        sy[bb]  = fsig(py[bb]);
        scf[bb] = fsig(pf[bb]);
        aw[bb]  = fabsf(pw[bb]);
        ah[bb]  = fabsf(ph[bb]);
        const float p1x = sx[bb] - aw[bb] * 0.5f, p1y = sy[bb] - ah[bb] * 0.5f;
        const float p2x = sx[bb] + aw[bb] * 0.5f, p2y = sy[bb] + ah[bb] * 0.5f;
        const float ix = fminf(p2x, t2x) - fmaxf(p1x, t1x);
        const float iy = fminf(p2y, t2y) - fmaxf(p1y, t1y);
        const float inter = fmaxf(ix, 0.0f) * fmaxf(iy, 0.0f);
        const float parea = aw[bb] * ah[bb];
        iou[bb] = inter * __builtin_amdgcn_rcpf(parea + tarea - inter + EPSV);
    }
    // jnp.argmax: first occurrence of max -> box1 only if strictly greater
    const int best = (iou[1] > iou[0]) ? 1 : 0;

    const float dx = sx[best] - tx;
    const float dy = sy[best] - ty;
    const float dw = __builtin_amdgcn_sqrtf(aw[best] + EPSV) -
                     __builtin_amdgcn_sqrtf(tw + EPSV);
    const float dh = __builtin_amdgcn_sqrtf(ah[best] + EPSV) -
                     __builtin_amdgcn_sqrtf(th + EPSV);
    acc_coord += LAMBDA_COORD * obj * ((dx * dx + dy * dy) + (dw * dw + dh * dh));

    const float sc = scf[best];
    acc_cobj += obj * (sc - tconf) * (sc - tconf);

    const float d0 = scf[0] - tconf;
    const float d1 = scf[1] - tconf;
    acc_cnoobj += LAMBDA_NOOBJ * noobj * (d0 * d0 + d1 * d1);

    const float pc = c3.z;
    const float bce = fmaxf(pc, 0.0f) - pc * tcls +
                      __logf(1.0f + __expf(-fabsf(pc)));
    acc_cls += obj * bce;
}

__global__ __launch_bounds__(TPB) void yolo_partial_kernel(
    const float* __restrict__ pred,
    const float* __restrict__ tgt,
    float* __restrict__ partials)   // gridDim.x float4s
{
    __shared__ float red[4][4];
    const int tid = threadIdx.x;
    const long long c0 = (long long)blockIdx.x * (TPB * 2) + tid;
    const long long c1 = c0 + TPB;

    // ---- issue all loads up front (deep MLP), nt-bit streaming ----
    const float* p0 = pred + c0 * PRED_C;
    const float* p1 = pred + c1 * PRED_C;
    const float* t0 = tgt  + c0 * TGT_C;
    const float* t1 = tgt  + c1 * TGT_C;

    const f4u a0  = nt4(p0);
    const f4u b0  = nt4(p0 + 4);
    const f3u cc0 = nt3(p0 + 8);
    const f4u a1  = nt4(p1);
    const f4u b1  = nt4(p1 + 4);
    const f3u cc1 = nt3(p1 + 8);
    const f4u t40 = nt4(t0);
    const f2u t20 = nt2(t0 + 4);
    const f4u t41 = nt4(t1);
    const f2u t21 = nt2(t1 + 4);

    float coord = 0.f, cobj = 0.f, cnoobj = 0.f, cls = 0.f;
    cell_loss(a0, b0, cc0, t40, t20, coord, cobj, cnoobj, cls);
    cell_loss(a1, b1, cc1, t41, t21, coord, cobj, cnoobj, cls);

    // ---- reduction: wave shuffle (64-wide) -> cross-wave LDS -> float4 store
    #pragma unroll
    for (int off = 32; off >= 1; off >>= 1) {
        coord  += __shfl_down(coord, off);
        cobj   += __shfl_down(cobj, off);
        cnoobj += __shfl_down(cnoobj, off);
        cls    += __shfl_down(cls, off);
    }
    const int wave = tid >> 6;
    const int lane = tid & 63;
    if (lane == 0) {
        red[wave][0] = coord;
        red[wave][1] = cobj;
        red[wave][2] = cnoobj;
        red[wave][3] = cls;
    }
    __syncthreads();
    if (tid == 0) {
        float4 v;
        v.x = red[0][0] + red[1][0] + red[2][0] + red[3][0];
        v.y = red[0][1] + red[1][1] + red[2][1] + red[3][1];
        v.z = red[0][2] + red[1][2] + red[2][2] + red[3][2];
        v.w = red[0][3] + red[1][3] + red[2][3] + red[3][3];
        ((float4*)partials)[blockIdx.x] = v;
    }
}

__global__ __launch_bounds__(1024) void yolo_final_kernel(
    const float* __restrict__ partials,
    float* __restrict__ out,
    int nblk,
    float inv_bs)
{
    __shared__ float red[16][4];
    const int tid = threadIdx.x;

    float c = 0.f, co = 0.f, cn = 0.f, cl = 0.f;
    for (int i = tid; i < nblk; i += 1024) {
        const float4 v = ((const float4*)partials)[i];
        c += v.x; co += v.y; cn += v.z; cl += v.w;
    }
    #pragma unroll
    for (int off = 32; off >= 1; off >>= 1) {
        c  += __shfl_down(c, off);
        co += __shfl_down(co, off);
        cn += __shfl_down(cn, off);
        cl += __shfl_down(cl, off);
    }
    const int wave = tid >> 6;
    const int lane = tid & 63;
    if (lane == 0) {
        red[wave][0] = c;
        red[wave][1] = co;
        red[wave][2] = cn;
        red[wave][3] = cl;
    }
    __syncthreads();
    if (tid == 0) {
        float sc = 0.f, sco = 0.f, scn = 0.f, scl = 0.f;
        #pragma unroll
        for (int w = 0; w < 16; ++w) {
            sc  += red[w][0];
            sco += red[w][1];
            scn += red[w][2];
            scl += red[w][3];
        }
        out[0] = (sc + sco + scn + scl) * inv_bs;
        out[1] = sc  * inv_bs;
        out[2] = sco * inv_bs;
        out[3] = scn * inv_bs;
        out[4] = scl * inv_bs;
    }
}

extern "C" void kernel_launch(void* const* d_in, const int* in_sizes, int n_in,
                              void* d_out, int out_size, void* d_ws, size_t ws_size,
                              hipStream_t stream) {
    const float* pred = (const float*)d_in[0];
    const float* tgt  = (const float*)d_in[1];
    float* out = (float*)d_out;
    float* partials = (float*)d_ws;

    const long long batch = (long long)in_sizes[0] / (7 * 7 * PRED_C);
    const long long cells = batch * 49;              // 1,605,632
    const int nblk = (int)(cells / (TPB * 2));       // 3136 exact

    yolo_partial_kernel<<<nblk, TPB, 0, stream>>>(pred, tgt, partials);
    yolo_final_kernel<<<1, 1024, 0, stream>>>(partials, out, nblk,
                                              1.0f / (float)batch);
}